// Round 4
// baseline (371.207 us; speedup 1.0000x reference)
//
#include <hip/hip_runtime.h>
#include <stdint.h>

#define M_TOT 2048   // B*C
#define N_TOT 16384  // B*F
#define K_TOT 512    // D

typedef _Float16 f16x8 __attribute__((ext_vector_type(8)));
typedef float f32x4 __attribute__((ext_vector_type(4)));
typedef float f32x16 __attribute__((ext_vector_type(16)));

#define AS1 __attribute__((address_space(1)))
#define AS3 __attribute__((address_space(3)))

__device__ __forceinline__ void ld_lds16(const void* g, void* l) {
    __builtin_amdgcn_global_load_lds((const AS1 void*)g, (AS3 void*)l, 16, 0, 0);
}

// ---------------- Kernel 1: norms + f16 hi/lo split planes ----------------
__device__ __forceinline__ void split4(float x0, float x1, float x2, float x3,
                                       uint2* hs, uint2* ls) {
    union U { _Float16 h[4]; uint2 u; } H, L;
    _Float16 h0 = (_Float16)x0; H.h[0] = h0; L.h[0] = (_Float16)(x0 - (float)h0);
    _Float16 h1 = (_Float16)x1; H.h[1] = h1; L.h[1] = (_Float16)(x1 - (float)h1);
    _Float16 h2 = (_Float16)x2; H.h[2] = h2; L.h[2] = (_Float16)(x2 - (float)h2);
    _Float16 h3 = (_Float16)x3; H.h[3] = h3; L.h[3] = (_Float16)(x3 - (float)h3);
    *hs = H.u; *ls = L.u;
}

__global__ __launch_bounds__(256) void norm_split_kernel(
    const float* __restrict__ c_feats, const float* __restrict__ f_feats,
    _Float16* __restrict__ Ah, _Float16* __restrict__ Al,
    _Float16* __restrict__ Bh, _Float16* __restrict__ Bl,
    float* __restrict__ normf)
{
    int wave = blockIdx.x * 4 + (threadIdx.x >> 6);
    int lane = threadIdx.x & 63;
    if (wave < 2048) {
        const float* row = c_feats + (size_t)wave * K_TOT;
        float4 v0 = ((const float4*)row)[lane];
        float4 v1 = ((const float4*)row)[lane + 64];
        double ss = (double)v0.x * v0.x + (double)v0.y * v0.y +
                    (double)v0.z * v0.z + (double)v0.w * v0.w +
                    (double)v1.x * v1.x + (double)v1.y * v1.y +
                    (double)v1.z * v1.z + (double)v1.w * v1.w;
        #pragma unroll
        for (int off = 32; off; off >>= 1) ss += __shfl_down(ss, off);
        double tot = __shfl(ss, 0);
        float nrm = sqrtf((float)tot);
        float a0 = v0.x / nrm, a1 = v0.y / nrm, a2 = v0.z / nrm, a3 = v0.w / nrm;
        float b0 = v1.x / nrm, b1 = v1.y / nrm, b2 = v1.z / nrm, b3 = v1.w / nrm;
        uint2 h, l;
        split4(a0, a1, a2, a3, &h, &l);
        ((uint2*)(Ah + (size_t)wave * K_TOT))[lane] = h;
        ((uint2*)(Al + (size_t)wave * K_TOT))[lane] = l;
        split4(b0, b1, b2, b3, &h, &l);
        ((uint2*)(Ah + (size_t)wave * K_TOT))[lane + 64] = h;
        ((uint2*)(Al + (size_t)wave * K_TOT))[lane + 64] = l;
    } else if (wave < 18432) {
        int fr = wave - 2048;
        const float* row = f_feats + (size_t)fr * K_TOT;
        float4 v0 = ((const float4*)row)[lane];
        float4 v1 = ((const float4*)row)[lane + 64];
        double ss = (double)v0.x * v0.x + (double)v0.y * v0.y +
                    (double)v0.z * v0.z + (double)v0.w * v0.w +
                    (double)v1.x * v1.x + (double)v1.y * v1.y +
                    (double)v1.z * v1.z + (double)v1.w * v1.w;
        #pragma unroll
        for (int off = 32; off; off >>= 1) ss += __shfl_down(ss, off);
        if (lane == 0) normf[fr] = sqrtf((float)ss);
        uint2 h, l;
        split4(v0.x, v0.y, v0.z, v0.w, &h, &l);
        ((uint2*)(Bh + (size_t)fr * K_TOT))[lane] = h;
        ((uint2*)(Bl + (size_t)fr * K_TOT))[lane] = l;
        split4(v1.x, v1.y, v1.z, v1.w, &h, &l);
        ((uint2*)(Bh + (size_t)fr * K_TOT))[lane + 64] = h;
        ((uint2*)(Bl + (size_t)fr * K_TOT))[lane + 64] = l;
    }
}

// ---------------- Kernel 2: FUSED split-f16 MFMA GEMM + wavefront DTW ----------------
// One 128x128 GEMM block = 8 complete DTW problems. S never touches HBM.
//
// R4 DTW-phase redesign (R3's 116us phase was an LDS-latency chain at 240cyc/step):
//  - S stored TIME-SKEWED: addr = p*SPS + r*SRS + (col + r). At DP step t every
//    lane reads the SAME offset t from its own row -> sv loads become one
//    ds_read_b128 per 4 steps, prefetched 4 chunks (16 steps, ~300cyc) ahead
//    through a statically-indexed 4-register ring. Step cost ~18cyc (VALU chain).
//  - SRS=148 (mult of 4 -> 16B aligned; 148==20 mod 32 -> lane bank-starts
//    {0,4,..,28}x2 cover all 32 banks uniformly: 8 hits/bank = zero excess).
//  - All 64 lanes active: waves 0-1 run 4 problems each (8 total); waves 2-3
//    sleep at the barrier, then help write masks.
// S values, DP arithmetic, traversal order bit-identical to R2/R3 -> absmax 0.
#define SRS 148      // S row stride (floats), >=143 (skew extends row to 143)
#define SPS 2368     // S problem stride: 16*148

__device__ __forceinline__ float dpp_shr1_f32(float x) {
    union { float f; int i; } u, v;
    u.f = x;
    v.i = __builtin_amdgcn_update_dpp(u.i, u.i, 0x111, 0xF, 0xF, false);
    return v.f;
}

__global__ __launch_bounds__(256, 2) void gemm_dtw_kernel(
    const _Float16* __restrict__ Ah, const _Float16* __restrict__ Al,
    const _Float16* __restrict__ Bh, const _Float16* __restrict__ Bl,
    const float* __restrict__ normf,
    float* __restrict__ out)
{
    // 75776 B; first 32 KiB doubles as the GEMM staging buffers (staging dead
    // after the K-loop's trailing __syncthreads, before the first S write).
    // Total LDS 80512 B -> 2 blocks/CU (2*80512 = 161024 <= 163840).
    __shared__ __attribute__((aligned(16))) float S[8 * SPS];
    __shared__ uint32_t mv[8][132];      // 4224 B
    __shared__ int bounds[8][16];        // 512 B

    _Float16* const sAh = (_Float16*)S;
    _Float16* const sAl = sAh + 128 * 32;
    _Float16* const sBh = sAl + 128 * 32;
    _Float16* const sBl = sBh + 128 * 32;

    const int t = threadIdx.x;
    const int w = t >> 6, lane = t & 63;
    const int ntile = ((blockIdx.x & 7) << 4) | (blockIdx.x >> 3);
    const int gm0 = blockIdx.y * 128, gn0 = ntile * 128;
    const int wm = (w & 1) * 64, wn = (w >> 1) * 64;
    const int m32 = lane & 31;
    const int kql0 = lane >> 5;

    f32x16 acc[2][2] = {};
    const int l0 = w * 128 + lane;

    for (int k0 = 0; k0 < K_TOT; k0 += 32) {
        #pragma unroll
        for (int c = 0; c < 2; ++c) {
            int l = l0 + c * 64;
            int lrow = l >> 2, kq = l & 3;
            int kqs = kq ^ ((lrow >> 1) & 3);
            size_t goffA = (size_t)(gm0 + lrow) * K_TOT + k0 + kqs * 8;
            size_t goffB = (size_t)(gn0 + lrow) * K_TOT + k0 + kqs * 8;
            ld_lds16(Ah + goffA, sAh + (size_t)l * 8);
            ld_lds16(Al + goffA, sAl + (size_t)l * 8);
            ld_lds16(Bh + goffB, sBh + (size_t)l * 8);
            ld_lds16(Bl + goffB, sBl + (size_t)l * 8);
        }
        __syncthreads();

        #pragma unroll
        for (int kh = 0; kh < 2; ++kh) {
            f16x8 fah[2], fal[2], fbh[2], fbl[2];
            #pragma unroll
            for (int x = 0; x < 2; ++x) {
                int arr = wm + x * 32 + m32;
                int brr = wn + x * 32 + m32;
                int kqa = (kh * 2 + kql0) ^ ((arr >> 1) & 3);
                int kqb = (kh * 2 + kql0) ^ ((brr >> 1) & 3);
                int ar = arr * 32 + kqa * 8;
                int br = brr * 32 + kqb * 8;
                fah[x] = *(const f16x8*)(sAh + ar);
                fal[x] = *(const f16x8*)(sAl + ar);
                fbh[x] = *(const f16x8*)(sBh + br);
                fbl[x] = *(const f16x8*)(sBl + br);
            }
            #pragma unroll
            for (int mi = 0; mi < 2; ++mi)
                #pragma unroll
                for (int ni = 0; ni < 2; ++ni) {
                    acc[mi][ni] = __builtin_amdgcn_mfma_f32_32x32x16_f16(fah[mi], fbl[ni], acc[mi][ni], 0, 0, 0);
                    acc[mi][ni] = __builtin_amdgcn_mfma_f32_32x32x16_f16(fal[mi], fbh[ni], acc[mi][ni], 0, 0, 0);
                    acc[mi][ni] = __builtin_amdgcn_mfma_f32_32x32x16_f16(fah[mi], fbh[ni], acc[mi][ni], 0, 0, 0);
                }
        }
        __syncthreads();
    }

    // ---- epilogue: norm-correct + S -> LDS (time-skewed DTW layout) ----
    // Write banks: within each 32-lane half, rg fixed and col consecutive ->
    // 32 consecutive floats -> all 32 banks once. Skew only shifts the base.
    const int rq = 4 * kql0;
    #pragma unroll
    for (int ni = 0; ni < 2; ++ni) {
        const int col = wn + ni * 32 + m32;
        const bool cn = (col < 16);
        const float nf = cn ? normf[gn0 + col] : 1.f;
        #pragma unroll
        for (int mi = 0; mi < 2; ++mi) {
            #pragma unroll
            for (int reg = 0; reg < 16; ++reg) {
                const int rg = wm + mi * 32 + (reg & 3) + 8 * (reg >> 2) + rq;
                const int rr = rg & 15;
                float v = acc[mi][ni][reg];
                if (cn && col <= rr) v /= nf;
                S[(rg >> 4) * SPS + rr * SRS + col + rr] = v;
            }
        }
    }
    __syncthreads();   // S for a problem comes from 2 waves (col halves)

    // ---- DP: waves 0-1, 4 problems each (all 64 lanes active) ----
    const int q = lane >> 4, r = lane & 15;
    if (w < 2) {
        const int p = w * 4 + q;
        const float* Sp = S + p * SPS + r * SRS;
        uint32_t* mvq = &mv[p][0];

        const float NEG = -1e30f;
        float Dp = NEG, rawprev = NEG;
        uint32_t mvbuf = 0;
        int j = -r;

        // prefetch ring: 4 chunks (16 steps) ahead of use
        f32x4 ch[4];
        #pragma unroll
        for (int c0 = 0; c0 < 4; ++c0) ch[c0] = *(const f32x4*)(Sp + 4 * c0);

#define DTW_STEP(T, SV)                                                         \
    {                                                                           \
        float upr = dpp_shr1_f32(Dp);                                           \
        float dg = rawprev;                                                     \
        rawprev = upr;                                                          \
        float up = (r == 0) ? NEG : upr;                                        \
        float lf = Dp;                                                          \
        if ((T) < 16) {                                                         \
            if (j == 0) { lf = NEG; dg = (r == 0) ? 0.0f : NEG; }               \
            else if (r == 0) dg = NEG;                                          \
        } else {                                                                \
            if (r == 0) dg = NEG;                                               \
        }                                                                       \
        int m = (up >= lf && up >= dg) ? 0 : ((lf >= dg) ? 1 : 2);              \
        float Dc = fmaxf(up, fmaxf(lf, dg)) + (SV);                             \
        if ((unsigned)j < 128u) {                                               \
            mvbuf |= (uint32_t)m << (2 * (j & 15));                             \
            if ((j & 15) == 15) { mvq[r * 8 + (j >> 4)] = mvbuf; mvbuf = 0; }   \
        }                                                                       \
        Dp = Dc;                                                                \
        ++j;                                                                    \
    }

        #pragma unroll
        for (int g = 0; g < 36; ++g) {
            f32x4 cur = ch[g & 3];
            if (g + 4 < 36) ch[g & 3] = *(const f32x4*)(Sp + 4 * (g + 4));
            #pragma unroll
            for (int e = 0; e < 4; ++e) {
                const int T = g * 4 + e;
                if (T < 143) DTW_STEP(T, cur[e])
            }
        }
#undef DTW_STEP

        // ---- backtrack: leader lane of each 16-lane group (same wave: mv
        // writes/reads ordered by instruction order, no barrier needed) ----
        if (r == 0) {
            int i = 16, jj = 128, hic = 127;
            int cidx = -1;
            uint32_t word = 0;
            for (int it = 0; it < 160; ++it) {
                if (i <= 0) break;
                int idx = (i - 1) * 8 + ((jj - 1) >> 4);
                if (idx != cidx) { word = mvq[idx]; cidx = idx; }
                int m = (int)((word >> (2 * ((jj - 1) & 15))) & 3u);
                if (m == 1) { --jj; continue; }
                bounds[p][i - 1] = (jj - 1) | (hic << 8);
                if (m == 2) --jj;
                --i;
                hic = jj - 1;
            }
        }
    }
    __syncthreads();   // bounds now read by all 4 waves

    // ---- mask write: per wave 2 problems x 2048 floats, coalesced float4 ----
    const int nn = ntile;
    const int mmb = gm0 >> 4;
    #pragma unroll 4
    for (int it = 0; it < 16; ++it) {
        int flat = it * 64 + lane;
        int q2 = flat >> 9;
        int rem = flat & 511;
        int ii = rem >> 5;
        int c4 = rem & 31;
        int b = bounds[w * 2 + q2][ii];
        int lo = b & 0xff, hi = (b >> 8) & 0xff;
        int j0 = c4 * 4;
        float4 v;
        v.x = (j0 + 0 >= lo && j0 + 0 <= hi) ? 1.f : 0.f;
        v.y = (j0 + 1 >= lo && j0 + 1 <= hi) ? 1.f : 0.f;
        v.z = (j0 + 2 >= lo && j0 + 2 <= hi) ? 1.f : 0.f;
        v.w = (j0 + 3 >= lo && j0 + 3 <= hi) ? 1.f : 0.f;
        float* tb = out + ((size_t)((mmb + w * 2 + q2) * 128 + nn)) * 2048;
        *(float4*)(tb + ii * 128 + j0) = v;
    }
}

extern "C" void kernel_launch(void* const* d_in, const int* in_sizes, int n_in,
                              void* d_out, int out_size, void* d_ws, size_t ws_size,
                              hipStream_t stream)
{
    const float* c_feats = (const float*)d_in[0];
    const float* f_feats = (const float*)d_in[1];
    float* out = (float*)d_out;

    _Float16* Ah = (_Float16*)d_ws;
    _Float16* Al = Ah + (size_t)M_TOT * K_TOT;
    _Float16* Bh = Al + (size_t)M_TOT * K_TOT;
    _Float16* Bl = Bh + (size_t)N_TOT * K_TOT;
    float* normf = (float*)(Bl + (size_t)N_TOT * K_TOT);

    norm_split_kernel<<<4608, 256, 0, stream>>>(c_feats, f_feats, Ah, Al, Bh, Bl, normf);
    dim3 g(N_TOT / 128, M_TOT / 128);
    gemm_dtw_kernel<<<g, 256, 0, stream>>>(Ah, Al, Bh, Bl, normf, out);
}

// Round 5
// 336.570 us; speedup vs baseline: 1.1029x; 1.1029x over previous
//
#include <hip/hip_runtime.h>
#include <stdint.h>

#define M_TOT 2048   // B*C
#define N_TOT 16384  // B*F
#define K_TOT 512    // D

typedef _Float16 f16x8 __attribute__((ext_vector_type(8)));
typedef float f32x16 __attribute__((ext_vector_type(16)));

#define AS1 __attribute__((address_space(1)))
#define AS3 __attribute__((address_space(3)))

__device__ __forceinline__ void ld_lds16(const void* g, void* l) {
    __builtin_amdgcn_global_load_lds((const AS1 void*)g, (AS3 void*)l, 16, 0, 0);
}

// ---------------- Kernel 1: norms + f16 hi/lo split planes ----------------
__device__ __forceinline__ void split4(float x0, float x1, float x2, float x3,
                                       uint2* hs, uint2* ls) {
    union U { _Float16 h[4]; uint2 u; } H, L;
    _Float16 h0 = (_Float16)x0; H.h[0] = h0; L.h[0] = (_Float16)(x0 - (float)h0);
    _Float16 h1 = (_Float16)x1; H.h[1] = h1; L.h[1] = (_Float16)(x1 - (float)h1);
    _Float16 h2 = (_Float16)x2; H.h[2] = h2; L.h[2] = (_Float16)(x2 - (float)h2);
    _Float16 h3 = (_Float16)x3; H.h[3] = h3; L.h[3] = (_Float16)(x3 - (float)h3);
    *hs = H.u; *ls = L.u;
}

__global__ __launch_bounds__(256) void norm_split_kernel(
    const float* __restrict__ c_feats, const float* __restrict__ f_feats,
    _Float16* __restrict__ Ah, _Float16* __restrict__ Al,
    _Float16* __restrict__ Bh, _Float16* __restrict__ Bl,
    float* __restrict__ normf)
{
    int wave = blockIdx.x * 4 + (threadIdx.x >> 6);
    int lane = threadIdx.x & 63;
    if (wave < 2048) {
        const float* row = c_feats + (size_t)wave * K_TOT;
        float4 v0 = ((const float4*)row)[lane];
        float4 v1 = ((const float4*)row)[lane + 64];
        double ss = (double)v0.x * v0.x + (double)v0.y * v0.y +
                    (double)v0.z * v0.z + (double)v0.w * v0.w +
                    (double)v1.x * v1.x + (double)v1.y * v1.y +
                    (double)v1.z * v1.z + (double)v1.w * v1.w;
        #pragma unroll
        for (int off = 32; off; off >>= 1) ss += __shfl_down(ss, off);
        double tot = __shfl(ss, 0);
        float nrm = sqrtf((float)tot);
        float a0 = v0.x / nrm, a1 = v0.y / nrm, a2 = v0.z / nrm, a3 = v0.w / nrm;
        float b0 = v1.x / nrm, b1 = v1.y / nrm, b2 = v1.z / nrm, b3 = v1.w / nrm;
        uint2 h, l;
        split4(a0, a1, a2, a3, &h, &l);
        ((uint2*)(Ah + (size_t)wave * K_TOT))[lane] = h;
        ((uint2*)(Al + (size_t)wave * K_TOT))[lane] = l;
        split4(b0, b1, b2, b3, &h, &l);
        ((uint2*)(Ah + (size_t)wave * K_TOT))[lane + 64] = h;
        ((uint2*)(Al + (size_t)wave * K_TOT))[lane + 64] = l;
    } else if (wave < 18432) {
        int fr = wave - 2048;
        const float* row = f_feats + (size_t)fr * K_TOT;
        float4 v0 = ((const float4*)row)[lane];
        float4 v1 = ((const float4*)row)[lane + 64];
        double ss = (double)v0.x * v0.x + (double)v0.y * v0.y +
                    (double)v0.z * v0.z + (double)v0.w * v0.w +
                    (double)v1.x * v1.x + (double)v1.y * v1.y +
                    (double)v1.z * v1.z + (double)v1.w * v1.w;
        #pragma unroll
        for (int off = 32; off; off >>= 1) ss += __shfl_down(ss, off);
        if (lane == 0) normf[fr] = sqrtf((float)ss);
        uint2 h, l;
        split4(v0.x, v0.y, v0.z, v0.w, &h, &l);
        ((uint2*)(Bh + (size_t)fr * K_TOT))[lane] = h;
        ((uint2*)(Bl + (size_t)fr * K_TOT))[lane] = l;
        split4(v1.x, v1.y, v1.z, v1.w, &h, &l);
        ((uint2*)(Bh + (size_t)fr * K_TOT))[lane + 64] = h;
        ((uint2*)(Bl + (size_t)fr * K_TOT))[lane + 64] = l;
    }
}

// ---------------- Kernel 2: split-f16 MFMA GEMM (32x32x16) + XOR-swizzled LDS ----------------
// R2-proven structure (121 us, MfmaUtil 40%): 128x128 tile, 4 waves, 2-barrier
// K-loop, 4 blocks/CU. Fusion with DTW (R3/R4) was a net loss — reverted.
__global__ __launch_bounds__(256, 4) void mfma_gemm_kernel(
    const _Float16* __restrict__ Ah, const _Float16* __restrict__ Al,
    const _Float16* __restrict__ Bh, const _Float16* __restrict__ Bl,
    const float* __restrict__ normf,
    float* __restrict__ out)
{
    __shared__ _Float16 sAh[128 * 32];
    __shared__ _Float16 sAl[128 * 32];
    __shared__ _Float16 sBh[128 * 32];
    __shared__ _Float16 sBl[128 * 32];

    const int t = threadIdx.x;
    const int w = t >> 6, lane = t & 63;
    const int ntile = ((blockIdx.x & 7) << 4) | (blockIdx.x >> 3);
    const int gm0 = blockIdx.y * 128, gn0 = ntile * 128;
    const int wm = (w & 1) * 64, wn = (w >> 1) * 64;
    const int m32 = lane & 31;
    const int kql0 = lane >> 5;

    f32x16 acc[2][2] = {};
    const int l0 = w * 128 + lane;

    for (int k0 = 0; k0 < K_TOT; k0 += 32) {
        #pragma unroll
        for (int c = 0; c < 2; ++c) {
            int l = l0 + c * 64;
            int lrow = l >> 2, kq = l & 3;
            int kqs = kq ^ ((lrow >> 1) & 3);
            size_t goffA = (size_t)(gm0 + lrow) * K_TOT + k0 + kqs * 8;
            size_t goffB = (size_t)(gn0 + lrow) * K_TOT + k0 + kqs * 8;
            ld_lds16(Ah + goffA, sAh + (size_t)l * 8);
            ld_lds16(Al + goffA, sAl + (size_t)l * 8);
            ld_lds16(Bh + goffB, sBh + (size_t)l * 8);
            ld_lds16(Bl + goffB, sBl + (size_t)l * 8);
        }
        __syncthreads();

        #pragma unroll
        for (int kh = 0; kh < 2; ++kh) {
            f16x8 fah[2], fal[2], fbh[2], fbl[2];
            #pragma unroll
            for (int x = 0; x < 2; ++x) {
                int arr = wm + x * 32 + m32;
                int brr = wn + x * 32 + m32;
                int kqa = (kh * 2 + kql0) ^ ((arr >> 1) & 3);
                int kqb = (kh * 2 + kql0) ^ ((brr >> 1) & 3);
                int ar = arr * 32 + kqa * 8;
                int br = brr * 32 + kqb * 8;
                fah[x] = *(const f16x8*)(sAh + ar);
                fal[x] = *(const f16x8*)(sAl + ar);
                fbh[x] = *(const f16x8*)(sBh + br);
                fbl[x] = *(const f16x8*)(sBl + br);
            }
            #pragma unroll
            for (int mi = 0; mi < 2; ++mi)
                #pragma unroll
                for (int ni = 0; ni < 2; ++ni) {
                    acc[mi][ni] = __builtin_amdgcn_mfma_f32_32x32x16_f16(fah[mi], fbl[ni], acc[mi][ni], 0, 0, 0);
                    acc[mi][ni] = __builtin_amdgcn_mfma_f32_32x32x16_f16(fal[mi], fbh[ni], acc[mi][ni], 0, 0, 0);
                    acc[mi][ni] = __builtin_amdgcn_mfma_f32_32x32x16_f16(fah[mi], fbh[ni], acc[mi][ni], 0, 0, 0);
                }
        }
        __syncthreads();
    }

    const int nn = ntile;
    const int rq = 4 * (lane >> 5);
    #pragma unroll
    for (int ni = 0; ni < 2; ++ni) {
        int col = wn + ni * 32 + m32;
        bool cn = (col < 16);
        float nf = cn ? normf[gn0 + col] : 1.f;
        #pragma unroll
        for (int mi = 0; mi < 2; ++mi) {
            #pragma unroll
            for (int reg = 0; reg < 16; ++reg) {
                int r = wm + mi * 32 + (reg & 3) + 8 * (reg >> 2) + rq;
                int gm = gm0 + r;
                int mm = gm >> 4, ii = gm & 15;
                float v = acc[mi][ni][reg];
                if (cn && col <= ii) v /= nf;
                out[(((size_t)mm * 128 + nn) * 16 + ii) * 128 + col] = v;
            }
        }
    }
}

// ---------------- Kernel 3: wavefront DTW, single-wave blocks ----------------
// R5 re-granularization: 4096 blocks x 64 threads x 4 problems (was 1024 x 256
// x 16). LDS 12.1 KB/block -> 13 co-resident blocks/CU (3328 slots for 4096
// blocks) vs 3 (768 slots for 1024): the ~1-block-duration dispatch tail that
// held the kernel at ~2x its 41 us traffic floor shrinks ~4x, and 3+ waves/SIMD
// of TLP hide the serial DP chain. DP arithmetic, S window layout (WQS=304 bank
// fix), traversal and mask writes are byte-identical to the R2-proven kernel.
#define WQS 304        // per-problem stride (floats): 16*18 + 16 (==16 mod 32)
#define WBUF 1216      // per-buffer stride: 4*WQS

__device__ __forceinline__ float dpp_shr1_f32(float x) {
    union { float f; int i; } u, v;
    u.f = x;
    v.i = __builtin_amdgcn_update_dpp(u.i, u.i, 0x111, 0xF, 0xF, false);
    return v.f;
}

__global__ __launch_bounds__(64) void dtw_kernel(float* __restrict__ buf)
{
    __shared__ float swin[2 * WBUF];     // 9728 B
    __shared__ uint32_t mvw[4][132];     // 2112 B
    __shared__ int bounds[4][16];        // 256 B

    const int lane = threadIdx.x & 63;
    const int q = lane >> 4, r = lane & 15;
    const int pbase = (4095 - (int)blockIdx.x) * 4;
    const float4* gbase = (const float4*)(buf + (size_t)pbase * 2048);
    float* sw = swin;
    uint32_t* mvq = &mvw[q][0];

    // staging tables: 4 float4 per lane per 16-col window; store i covers problem q=i
    int gidx[4], lidx[4];
    #pragma unroll
    for (int i = 0; i < 4; ++i) {
        gidx[i] = i * 512 + ((lane >> 2) & 15) * 32 + (lane & 3);
        lidx[i] = i * WQS + ((lane >> 2) & 15) * 18 + (lane & 3) * 4;
    }

#define WSTORE(regs, boff)                                                      \
    {                                                                           \
        _Pragma("unroll")                                                       \
        for (int i = 0; i < 4; ++i) {                                           \
            *(float2*)(sw + (boff) + lidx[i])     = make_float2(regs[i].x, regs[i].y); \
            *(float2*)(sw + (boff) + lidx[i] + 2) = make_float2(regs[i].z, regs[i].w); \
        }                                                                       \
    }
#define WLOAD(regs, win)                                                        \
    {                                                                           \
        _Pragma("unroll")                                                       \
        for (int i = 0; i < 4; ++i) regs[i] = gbase[gidx[i] + (win) * 4];       \
    }

    float4 ga[4], gb[4];
    WLOAD(ga, 0)                      // win0
    WLOAD(gb, 1)                      // win1
    WSTORE(ga, 0)                     // win0 -> buf0
    WSTORE(gb, WBUF)                  // win1 -> buf1
    WLOAD(ga, 2)                      // win2 in flight (used at t=32)
    WLOAD(gb, 3)                      // win3 in flight (used at t=48)

    const float NEG = -1e30f;
    float Dp = NEG, rawprev = NEG;
    uint32_t mvbuf = 0;
    int j = -r;
    const int sb = q * WQS + r * 18;

#define DTW_STEP(BOUNDARY)                                                      \
    {                                                                           \
        float upr = dpp_shr1_f32(Dp);                                           \
        float dg = rawprev;                                                     \
        rawprev = upr;                                                          \
        float up = (r == 0) ? NEG : upr;                                        \
        float lf = Dp;                                                          \
        if (BOUNDARY) {                                                         \
            if (j == 0) { lf = NEG; dg = (r == 0) ? 0.0f : NEG; }               \
            else if (r == 0) dg = NEG;                                          \
        } else {                                                                \
            if (r == 0) dg = NEG;                                               \
        }                                                                       \
        float sv = sw[(((j >> 4) & 1) ? WBUF : 0) + sb + (j & 15)];             \
        int m = (up >= lf && up >= dg) ? 0 : ((lf >= dg) ? 1 : 2);              \
        float Dc = fmaxf(up, fmaxf(lf, dg)) + sv;                               \
        if ((unsigned)j < 128u) {                                               \
            mvbuf |= (uint32_t)m << (2 * (j & 15));                             \
            if ((j & 15) == 15) { mvq[r * 8 + (j >> 4)] = mvbuf; mvbuf = 0; }   \
        }                                                                       \
        Dp = Dc;                                                                \
        ++j;                                                                    \
    }

    for (int t = 0; t < 16; ++t) DTW_STEP(true)
    for (int t = 16; t < 32; ++t) DTW_STEP(false)
    WSTORE(ga, 0)      /* win2 -> buf0 */  WLOAD(ga, 4)
    for (int t = 32; t < 48; ++t) DTW_STEP(false)
    WSTORE(gb, WBUF)   /* win3 -> buf1 */  WLOAD(gb, 5)
    for (int t = 48; t < 64; ++t) DTW_STEP(false)
    WSTORE(ga, 0)      /* win4 -> buf0 */  WLOAD(ga, 6)
    for (int t = 64; t < 80; ++t) DTW_STEP(false)
    WSTORE(gb, WBUF)   /* win5 -> buf1 */  WLOAD(gb, 7)
    for (int t = 80; t < 96; ++t) DTW_STEP(false)
    WSTORE(ga, 0)      /* win6 -> buf0 */
    for (int t = 96; t < 112; ++t) DTW_STEP(false)
    WSTORE(gb, WBUF)   /* win7 -> buf1 */
    for (int t = 112; t < 143; ++t) DTW_STEP(false)
#undef DTW_STEP
#undef WSTORE
#undef WLOAD

    __syncthreads();   // single-wave: cheap; orders mv writes vs leader reads

    // backtrack: leader lanes (0,16,32,48), word-cached move decode
    if (r == 0) {
        int i = 16, jj = 128, hic = 127;
        int cidx = -1;
        uint32_t word = 0;
        for (int it = 0; it < 160; ++it) {
            if (i <= 0) break;
            int idx = (i - 1) * 8 + ((jj - 1) >> 4);
            if (idx != cidx) { word = mvq[idx]; cidx = idx; }
            int m = (int)((word >> (2 * ((jj - 1) & 15))) & 3u);
            if (m == 1) { --jj; continue; }
            bounds[q][i - 1] = (jj - 1) | (hic << 8);
            if (m == 2) --jj;
            --i;
            hic = jj - 1;
        }
    }
    __syncthreads();   // bounds read across 16-lane groups

    // write masks: 4 problems * 2048 floats = 2048 float4, coalesced
    #pragma unroll 4
    for (int it = 0; it < 32; ++it) {
        int flat = it * 64 + lane;
        int q2 = flat >> 9;
        int rem = flat & 511;
        int ii = rem >> 5;
        int c4 = rem & 31;
        int b = bounds[q2][ii];
        int lo = b & 0xff, hi = (b >> 8) & 0xff;
        int j0 = c4 * 4;
        float4 v;
        v.x = (j0 + 0 >= lo && j0 + 0 <= hi) ? 1.f : 0.f;
        v.y = (j0 + 1 >= lo && j0 + 1 <= hi) ? 1.f : 0.f;
        v.z = (j0 + 2 >= lo && j0 + 2 <= hi) ? 1.f : 0.f;
        v.w = (j0 + 3 >= lo && j0 + 3 <= hi) ? 1.f : 0.f;
        float* tb = buf + (size_t)(pbase + q2) * 2048;
        *(float4*)(tb + ii * 128 + j0) = v;
    }
}

extern "C" void kernel_launch(void* const* d_in, const int* in_sizes, int n_in,
                              void* d_out, int out_size, void* d_ws, size_t ws_size,
                              hipStream_t stream)
{
    const float* c_feats = (const float*)d_in[0];
    const float* f_feats = (const float*)d_in[1];
    float* out = (float*)d_out;

    _Float16* Ah = (_Float16*)d_ws;
    _Float16* Al = Ah + (size_t)M_TOT * K_TOT;
    _Float16* Bh = Al + (size_t)M_TOT * K_TOT;
    _Float16* Bl = Bh + (size_t)N_TOT * K_TOT;
    float* normf = (float*)(Bl + (size_t)N_TOT * K_TOT);

    norm_split_kernel<<<4608, 256, 0, stream>>>(c_feats, f_feats, Ah, Al, Bh, Bl, normf);
    dim3 g(N_TOT / 128, M_TOT / 128);
    mfma_gemm_kernel<<<g, 256, 0, stream>>>(Ah, Al, Bh, Bl, normf, out);
    dtw_kernel<<<4096, 64, 0, stream>>>(out);
}

// Round 6
// 333.362 us; speedup vs baseline: 1.1135x; 1.0096x over previous
//
#include <hip/hip_runtime.h>
#include <stdint.h>

#define M_TOT 2048   // B*C
#define N_TOT 16384  // B*F
#define K_TOT 512    // D

typedef _Float16 f16x8 __attribute__((ext_vector_type(8)));
typedef float f32x16 __attribute__((ext_vector_type(16)));

#define AS1 __attribute__((address_space(1)))
#define AS3 __attribute__((address_space(3)))

__device__ __forceinline__ void ld_lds16(const void* g, void* l) {
    __builtin_amdgcn_global_load_lds((const AS1 void*)g, (AS3 void*)l, 16, 0, 0);
}

#define BAR() do { asm volatile("" ::: "memory"); __builtin_amdgcn_s_barrier(); asm volatile("" ::: "memory"); } while (0)
#define VMC4() asm volatile("s_waitcnt vmcnt(4)" ::: "memory")
#define VMC0() asm volatile("s_waitcnt vmcnt(0)" ::: "memory")

// ---------------- Kernel 1: norms + f16 hi/lo split planes ----------------
__device__ __forceinline__ void split4(float x0, float x1, float x2, float x3,
                                       uint2* hs, uint2* ls) {
    union U { _Float16 h[4]; uint2 u; } H, L;
    _Float16 h0 = (_Float16)x0; H.h[0] = h0; L.h[0] = (_Float16)(x0 - (float)h0);
    _Float16 h1 = (_Float16)x1; H.h[1] = h1; L.h[1] = (_Float16)(x1 - (float)h1);
    _Float16 h2 = (_Float16)x2; H.h[2] = h2; L.h[2] = (_Float16)(x2 - (float)h2);
    _Float16 h3 = (_Float16)x3; H.h[3] = h3; L.h[3] = (_Float16)(x3 - (float)h3);
    *hs = H.u; *ls = L.u;
}

__global__ __launch_bounds__(256) void norm_split_kernel(
    const float* __restrict__ c_feats, const float* __restrict__ f_feats,
    _Float16* __restrict__ Ah, _Float16* __restrict__ Al,
    _Float16* __restrict__ Bh, _Float16* __restrict__ Bl,
    float* __restrict__ normf)
{
    int wave = blockIdx.x * 4 + (threadIdx.x >> 6);
    int lane = threadIdx.x & 63;
    if (wave < 2048) {
        const float* row = c_feats + (size_t)wave * K_TOT;
        float4 v0 = ((const float4*)row)[lane];
        float4 v1 = ((const float4*)row)[lane + 64];
        double ss = (double)v0.x * v0.x + (double)v0.y * v0.y +
                    (double)v0.z * v0.z + (double)v0.w * v0.w +
                    (double)v1.x * v1.x + (double)v1.y * v1.y +
                    (double)v1.z * v1.z + (double)v1.w * v1.w;
        #pragma unroll
        for (int off = 32; off; off >>= 1) ss += __shfl_down(ss, off);
        double tot = __shfl(ss, 0);
        float nrm = sqrtf((float)tot);
        float a0 = v0.x / nrm, a1 = v0.y / nrm, a2 = v0.z / nrm, a3 = v0.w / nrm;
        float b0 = v1.x / nrm, b1 = v1.y / nrm, b2 = v1.z / nrm, b3 = v1.w / nrm;
        uint2 h, l;
        split4(a0, a1, a2, a3, &h, &l);
        ((uint2*)(Ah + (size_t)wave * K_TOT))[lane] = h;
        ((uint2*)(Al + (size_t)wave * K_TOT))[lane] = l;
        split4(b0, b1, b2, b3, &h, &l);
        ((uint2*)(Ah + (size_t)wave * K_TOT))[lane + 64] = h;
        ((uint2*)(Al + (size_t)wave * K_TOT))[lane + 64] = l;
    } else if (wave < 18432) {
        int fr = wave - 2048;
        const float* row = f_feats + (size_t)fr * K_TOT;
        float4 v0 = ((const float4*)row)[lane];
        float4 v1 = ((const float4*)row)[lane + 64];
        double ss = (double)v0.x * v0.x + (double)v0.y * v0.y +
                    (double)v0.z * v0.z + (double)v0.w * v0.w +
                    (double)v1.x * v1.x + (double)v1.y * v1.y +
                    (double)v1.z * v1.z + (double)v1.w * v1.w;
        #pragma unroll
        for (int off = 32; off; off >>= 1) ss += __shfl_down(ss, off);
        if (lane == 0) normf[fr] = sqrtf((float)ss);
        uint2 h, l;
        split4(v0.x, v0.y, v0.z, v0.w, &h, &l);
        ((uint2*)(Bh + (size_t)fr * K_TOT))[lane] = h;
        ((uint2*)(Bl + (size_t)fr * K_TOT))[lane] = l;
        split4(v1.x, v1.y, v1.z, v1.w, &h, &l);
        ((uint2*)(Bh + (size_t)fr * K_TOT))[lane + 64] = h;
        ((uint2*)(Bl + (size_t)fr * K_TOT))[lane + 64] = l;
    }
}

// ---------------- Kernel 2: split-f16 MFMA GEMM, 256x256, 3-phase pipelined ----------------
// T3+T4+T5 port exploiting split-f16's pass structure: each K-tile (BK=32) runs
// 3 phases = 3 passes (ah*bl, al*bh, ah*bh), each needing only 2 of the 4 LDS
// planes. Staging of tile t+1 is plane-staggered (PH0: Ah,Bl; PH1: Al,Bh) so
// the per-phase wait is a counted vmcnt(4) -- FIFO completion means the oldest
// 4 loads are exactly the planes the next phase consumes. Never vmcnt(0) in the
// main loop. PH2 reuses PH0's Ah and PH1's Bh fragments from registers (24
// ds_read_b128/tile vs 36). LDS = 2 dbuf x 4 planes x 16KB = 128 KiB, 1 blk/CU,
// 8 waves (2M x 4N), per-wave 128x64 out, acc 4x2 f32x16.
// k-quad XOR swizzle + pre-swizzled global staging identical to the R2-proven
// kernel; epilogue identical to the R1-verified 256^2 epilogue.
__global__ __launch_bounds__(512, 2) void mfma_gemm_kernel(
    const _Float16* __restrict__ Ah, const _Float16* __restrict__ Al,
    const _Float16* __restrict__ Bh, const _Float16* __restrict__ Bl,
    const float* __restrict__ normf,
    float* __restrict__ out)
{
    __shared__ _Float16 lds[2 * 4 * 8192];   // [buf][plane: Ah,Al,Bh,Bl][256*32]

    const int t = threadIdx.x;
    const int w = t >> 6, lane = t & 63;
    const int m32 = lane & 31, kql0 = lane >> 5;
    const int wr = w >> 2, wc = w & 3;
    const int wm = wr * 128, wn = wc * 64;

    // n-tile-major swizzle (bijective on 64), same family as the R2-proven map
    const int bx = (int)blockIdx.x;
    const int ntile = ((bx & 7) << 3) | (bx >> 3);
    const int gm0 = (int)blockIdx.y * 256, gn0 = ntile * 256;

    // staging: thread covers chunks t and t+512 of each 256x32 plane.
    // chunk c: row=c>>2, kq=c&3, stored at slot kq with global kq' = kq^((row>>1)&3)
    const int rowA = t >> 2;
    const int kq8 = ((t & 3) ^ ((rowA >> 1) & 3)) * 8;
    const _Float16* const gA  = Ah + (size_t)(gm0 + rowA) * K_TOT + kq8;
    const _Float16* const gB  = Bh + (size_t)(gn0 + rowA) * K_TOT + kq8;
    const _Float16* const gAl2 = gA + (size_t)M_TOT * K_TOT;   // Al plane
    const _Float16* const gBl2 = gB + (size_t)N_TOT * K_TOT;   // Bl plane
    const int t8 = t * 8;
    // second chunk: +128 rows => +128*K_TOT = 65536 f16 global, +4096 f16 LDS

    // fragment ds_read offsets (f16 units) within a plane
    int aof[4][2], bof[2][2];
    #pragma unroll
    for (int mi = 0; mi < 4; ++mi) {
        int rr = wm + mi * 32 + m32;
        int x = (rr >> 1) & 3;
        #pragma unroll
        for (int kc = 0; kc < 2; ++kc)
            aof[mi][kc] = rr * 32 + (((kc * 2 + kql0) ^ x) * 8);
    }
    #pragma unroll
    for (int ni = 0; ni < 2; ++ni) {
        int rr = wn + ni * 32 + m32;
        int x = (rr >> 1) & 3;
        #pragma unroll
        for (int kc = 0; kc < 2; ++kc)
            bof[ni][kc] = rr * 32 + (((kc * 2 + kql0) ^ x) * 8);
    }

    f32x16 acc[4][2] = {};

    // ---- prologue: stage tile 0 (order: Ah, Bl, Al, Bh) ----
    {
        _Float16* L0 = lds + t8;
        ld_lds16(gA,            L0);
        ld_lds16(gA  + 65536,   L0 + 4096);
        ld_lds16(gBl2,          L0 + 3 * 8192);
        ld_lds16(gBl2 + 65536,  L0 + 3 * 8192 + 4096);
        ld_lds16(gAl2,          L0 + 1 * 8192);
        ld_lds16(gAl2 + 65536,  L0 + 1 * 8192 + 4096);
        ld_lds16(gB,            L0 + 2 * 8192);
        ld_lds16(gB  + 65536,   L0 + 2 * 8192 + 4096);
        VMC4();          // Ah(0), Bl(0) landed
        BAR();
    }

    #pragma unroll 1
    for (int tt = 0; tt < 16; ++tt) {
        const int cb = (tt & 1) << 15;           // current buffer (f16 offset)
        const _Float16* Lc = lds + cb;
        _Float16* Ln = lds + (cb ^ 32768) + t8;  // next-buffer staging dest
        const int kk = tt * 32 + 32;             // next tile's k offset
        const bool st = (tt < 15);

        f16x8 faH[4][2], fbH[2][2], faL[4][2], fbL[2][2];

        // ==== PH0: pass Ah x Bl ====
        #pragma unroll
        for (int mi = 0; mi < 4; ++mi)
            #pragma unroll
            for (int kc = 0; kc < 2; ++kc)
                faH[mi][kc] = *(const f16x8*)(Lc + aof[mi][kc]);
        #pragma unroll
        for (int ni = 0; ni < 2; ++ni)
            #pragma unroll
            for (int kc = 0; kc < 2; ++kc)
                fbL[ni][kc] = *(const f16x8*)(Lc + 3 * 8192 + bof[ni][kc]);
        if (st) {
            ld_lds16(gA   + kk,         Ln);
            ld_lds16(gA   + kk + 65536, Ln + 4096);
            ld_lds16(gBl2 + kk,         Ln + 3 * 8192);
            ld_lds16(gBl2 + kk + 65536, Ln + 3 * 8192 + 4096);
        }
        BAR();
        __builtin_amdgcn_s_setprio(1);
        #pragma unroll
        for (int mi = 0; mi < 4; ++mi)
            #pragma unroll
            for (int ni = 0; ni < 2; ++ni)
                #pragma unroll
                for (int kc = 0; kc < 2; ++kc)
                    acc[mi][ni] = __builtin_amdgcn_mfma_f32_32x32x16_f16(
                        faH[mi][kc], fbL[ni][kc], acc[mi][ni], 0, 0, 0);
        __builtin_amdgcn_s_setprio(0);
        if (st) VMC4(); else VMC0();   // Al(t), Bh(t) landed (oldest in queue)
        BAR();

        // ==== PH1: pass Al x Bh ====
        #pragma unroll
        for (int mi = 0; mi < 4; ++mi)
            #pragma unroll
            for (int kc = 0; kc < 2; ++kc)
                faL[mi][kc] = *(const f16x8*)(Lc + 1 * 8192 + aof[mi][kc]);
        #pragma unroll
        for (int ni = 0; ni < 2; ++ni)
            #pragma unroll
            for (int kc = 0; kc < 2; ++kc)
                fbH[ni][kc] = *(const f16x8*)(Lc + 2 * 8192 + bof[ni][kc]);
        if (st) {
            ld_lds16(gAl2 + kk,         Ln + 1 * 8192);
            ld_lds16(gAl2 + kk + 65536, Ln + 1 * 8192 + 4096);
            ld_lds16(gB   + kk,         Ln + 2 * 8192);
            ld_lds16(gB   + kk + 65536, Ln + 2 * 8192 + 4096);
        }
        BAR();
        __builtin_amdgcn_s_setprio(1);
        #pragma unroll
        for (int mi = 0; mi < 4; ++mi)
            #pragma unroll
            for (int ni = 0; ni < 2; ++ni)
                #pragma unroll
                for (int kc = 0; kc < 2; ++kc)
                    acc[mi][ni] = __builtin_amdgcn_mfma_f32_32x32x16_f16(
                        faL[mi][kc], fbH[ni][kc], acc[mi][ni], 0, 0, 0);
        __builtin_amdgcn_s_setprio(0);
        BAR();

        // ==== PH2: pass Ah x Bh (register reuse, no LDS) ====
        __builtin_amdgcn_s_setprio(1);
        #pragma unroll
        for (int mi = 0; mi < 4; ++mi)
            #pragma unroll
            for (int ni = 0; ni < 2; ++ni)
                #pragma unroll
                for (int kc = 0; kc < 2; ++kc)
                    acc[mi][ni] = __builtin_amdgcn_mfma_f32_32x32x16_f16(
                        faH[mi][kc], fbH[ni][kc], acc[mi][ni], 0, 0, 0);
        __builtin_amdgcn_s_setprio(0);
        if (st) VMC4();                // Ah(t+1), Bl(t+1) landed for next PH0
        BAR();
    }

    // ---- epilogue (R1-verified 256^2 form): norm-correct + store ----
    const int rq = 4 * kql0;
    #pragma unroll
    for (int ni = 0; ni < 2; ++ni) {
        const int gc = gn0 + wn + ni * 32 + m32;
        const int nn = gc >> 7;
        const int col = gc & 127;
        const bool cn = (col < 16);
        const float nf = cn ? normf[gc] : 1.f;
        #pragma unroll
        for (int mi = 0; mi < 4; ++mi) {
            #pragma unroll
            for (int reg = 0; reg < 16; ++reg) {
                const int gm = gm0 + wm + mi * 32 + (reg & 3) + 8 * (reg >> 2) + rq;
                const int mm = gm >> 4, ii = gm & 15;
                float v = acc[mi][ni][reg];
                if (cn && col <= ii) v /= nf;
                out[(((size_t)mm * 128 + nn) * 16 + ii) * 128 + col] = v;
            }
        }
    }
}

// ---------------- Kernel 3: wavefront DTW, single-wave blocks (R5) ----------------
#define WQS 304        // per-problem stride (floats): 16*18 + 16 (==16 mod 32)
#define WBUF 1216      // per-buffer stride: 4*WQS

__device__ __forceinline__ float dpp_shr1_f32(float x) {
    union { float f; int i; } u, v;
    u.f = x;
    v.i = __builtin_amdgcn_update_dpp(u.i, u.i, 0x111, 0xF, 0xF, false);
    return v.f;
}

__global__ __launch_bounds__(64) void dtw_kernel(float* __restrict__ buf)
{
    __shared__ float swin[2 * WBUF];
    __shared__ uint32_t mvw[4][132];
    __shared__ int bounds[4][16];

    const int lane = threadIdx.x & 63;
    const int q = lane >> 4, r = lane & 15;
    const int pbase = (4095 - (int)blockIdx.x) * 4;
    const float4* gbase = (const float4*)(buf + (size_t)pbase * 2048);
    float* sw = swin;
    uint32_t* mvq = &mvw[q][0];

    int gidx[4], lidx[4];
    #pragma unroll
    for (int i = 0; i < 4; ++i) {
        gidx[i] = i * 512 + ((lane >> 2) & 15) * 32 + (lane & 3);
        lidx[i] = i * WQS + ((lane >> 2) & 15) * 18 + (lane & 3) * 4;
    }

#define WSTORE(regs, boff)                                                      \
    {                                                                           \
        _Pragma("unroll")                                                       \
        for (int i = 0; i < 4; ++i) {                                           \
            *(float2*)(sw + (boff) + lidx[i])     = make_float2(regs[i].x, regs[i].y); \
            *(float2*)(sw + (boff) + lidx[i] + 2) = make_float2(regs[i].z, regs[i].w); \
        }                                                                       \
    }
#define WLOAD(regs, win)                                                        \
    {                                                                           \
        _Pragma("unroll")                                                       \
        for (int i = 0; i < 4; ++i) regs[i] = gbase[gidx[i] + (win) * 4];       \
    }

    float4 ga[4], gb[4];
    WLOAD(ga, 0)
    WLOAD(gb, 1)
    WSTORE(ga, 0)
    WSTORE(gb, WBUF)
    WLOAD(ga, 2)
    WLOAD(gb, 3)

    const float NEG = -1e30f;
    float Dp = NEG, rawprev = NEG;
    uint32_t mvbuf = 0;
    int j = -r;
    const int sb = q * WQS + r * 18;

#define DTW_STEP(BOUNDARY)                                                      \
    {                                                                           \
        float upr = dpp_shr1_f32(Dp);                                           \
        float dg = rawprev;                                                     \
        rawprev = upr;                                                          \
        float up = (r == 0) ? NEG : upr;                                        \
        float lf = Dp;                                                          \
        if (BOUNDARY) {                                                         \
            if (j == 0) { lf = NEG; dg = (r == 0) ? 0.0f : NEG; }               \
            else if (r == 0) dg = NEG;                                          \
        } else {                                                                \
            if (r == 0) dg = NEG;                                               \
        }                                                                       \
        float sv = sw[(((j >> 4) & 1) ? WBUF : 0) + sb + (j & 15)];             \
        int m = (up >= lf && up >= dg) ? 0 : ((lf >= dg) ? 1 : 2);              \
        float Dc = fmaxf(up, fmaxf(lf, dg)) + sv;                               \
        if ((unsigned)j < 128u) {                                               \
            mvbuf |= (uint32_t)m << (2 * (j & 15));                             \
            if ((j & 15) == 15) { mvq[r * 8 + (j >> 4)] = mvbuf; mvbuf = 0; }   \
        }                                                                       \
        Dp = Dc;                                                                \
        ++j;                                                                    \
    }

    for (int tt = 0; tt < 16; ++tt) DTW_STEP(true)
    for (int tt = 16; tt < 32; ++tt) DTW_STEP(false)
    WSTORE(ga, 0)      WLOAD(ga, 4)
    for (int tt = 32; tt < 48; ++tt) DTW_STEP(false)
    WSTORE(gb, WBUF)   WLOAD(gb, 5)
    for (int tt = 48; tt < 64; ++tt) DTW_STEP(false)
    WSTORE(ga, 0)      WLOAD(ga, 6)
    for (int tt = 64; tt < 80; ++tt) DTW_STEP(false)
    WSTORE(gb, WBUF)   WLOAD(gb, 7)
    for (int tt = 80; tt < 96; ++tt) DTW_STEP(false)
    WSTORE(ga, 0)
    for (int tt = 96; tt < 112; ++tt) DTW_STEP(false)
    WSTORE(gb, WBUF)
    for (int tt = 112; tt < 143; ++tt) DTW_STEP(false)
#undef DTW_STEP
#undef WSTORE
#undef WLOAD

    __syncthreads();

    if (r == 0) {
        int i = 16, jj = 128, hic = 127;
        int cidx = -1;
        uint32_t word = 0;
        for (int it = 0; it < 160; ++it) {
            if (i <= 0) break;
            int idx = (i - 1) * 8 + ((jj - 1) >> 4);
            if (idx != cidx) { word = mvq[idx]; cidx = idx; }
            int m = (int)((word >> (2 * ((jj - 1) & 15))) & 3u);
            if (m == 1) { --jj; continue; }
            bounds[q][i - 1] = (jj - 1) | (hic << 8);
            if (m == 2) --jj;
            --i;
            hic = jj - 1;
        }
    }
    __syncthreads();

    #pragma unroll 4
    for (int it = 0; it < 32; ++it) {
        int flat = it * 64 + lane;
        int q2 = flat >> 9;
        int rem = flat & 511;
        int ii = rem >> 5;
        int c4 = rem & 31;
        int b = bounds[q2][ii];
        int lo = b & 0xff, hi = (b >> 8) & 0xff;
        int j0 = c4 * 4;
        float4 v;
        v.x = (j0 + 0 >= lo && j0 + 0 <= hi) ? 1.f : 0.f;
        v.y = (j0 + 1 >= lo && j0 + 1 <= hi) ? 1.f : 0.f;
        v.z = (j0 + 2 >= lo && j0 + 2 <= hi) ? 1.f : 0.f;
        v.w = (j0 + 3 >= lo && j0 + 3 <= hi) ? 1.f : 0.f;
        float* tb = buf + (size_t)(pbase + q2) * 2048;
        *(float4*)(tb + ii * 128 + j0) = v;
    }
}

extern "C" void kernel_launch(void* const* d_in, const int* in_sizes, int n_in,
                              void* d_out, int out_size, void* d_ws, size_t ws_size,
                              hipStream_t stream)
{
    const float* c_feats = (const float*)d_in[0];
    const float* f_feats = (const float*)d_in[1];
    float* out = (float*)d_out;

    _Float16* Ah = (_Float16*)d_ws;
    _Float16* Al = Ah + (size_t)M_TOT * K_TOT;
    _Float16* Bh = Al + (size_t)M_TOT * K_TOT;
    _Float16* Bl = Bh + (size_t)N_TOT * K_TOT;
    float* normf = (float*)(Bl + (size_t)N_TOT * K_TOT);

    norm_split_kernel<<<4608, 256, 0, stream>>>(c_feats, f_feats, Ah, Al, Bh, Bl, normf);
    dim3 g(N_TOT / 256, M_TOT / 256);
    mfma_gemm_kernel<<<g, 512, 0, stream>>>(Ah, Al, Bh, Bl, normf, out);
    dtw_kernel<<<4096, 64, 0, stream>>>(out);
}